// Round 6
// baseline (130.853 us; speedup 1.0000x reference)
//
#include <hip/hip_runtime.h>
#include <hip/hip_bf16.h>

#define B_ 4
#define NIN_ 32
#define H_ 14
#define W_ 14
#define DIN_ 8
#define NOUT_ 32
#define DOUT_ 16
#define K_ 3
#define OH_ 12
#define OW_ 12
#define PROJ_ 512
#define HID_ 128
#define M_ 288                  // NIN*K*K
#define NPIX_ (B_*NIN_*H_*W_)   // 25088

typedef __attribute__((ext_vector_type(8))) short short8;
typedef __attribute__((ext_vector_type(4))) float f32x4;

__device__ __forceinline__ float bflo(unsigned int u) { return __uint_as_float(u << 16); }
__device__ __forceinline__ float bfhi(unsigned int u) { return __uint_as_float(u & 0xffff0000u); }
__device__ __forceinline__ float bf2f(unsigned short u) { return __uint_as_float(((unsigned int)u) << 16); }
__device__ __forceinline__ unsigned short bfbits(float f) {
    __hip_bfloat16 h = __float2bfloat16(f);
    return *(unsigned short*)&h;
}

// ---------------------------------------------------------------------------
// Prep: W2 (512x128) and W3 (128x512) f32 -> bf16 in MFMA B-fragment order.
// ---------------------------------------------------------------------------
__global__ __launch_bounds__(256) void prep_kernel(
    const float* __restrict__ W2, const float* __restrict__ W3,
    __hip_bfloat16* __restrict__ W2B, __hip_bfloat16* __restrict__ W3B)
{
    int idx = blockIdx.x * 256 + threadIdx.x;  // [0, 65536)
    {
        int j = idx & 7, lane = (idx >> 3) & 63, kt = (idx >> 9) & 15, nt = idx >> 13;
        int k = kt * 32 + (lane >> 4) * 8 + j;
        int c = nt * 16 + (lane & 15);
        W2B[idx] = __float2bfloat16(W2[k * HID_ + c]);
    }
    {
        int j = idx & 7, lane = (idx >> 3) & 63, kt = (idx >> 9) & 3, nt = idx >> 11;
        int k = kt * 32 + (lane >> 4) * 8 + j;
        int c = nt * 16 + (lane & 15);
        W3B[idx] = __float2bfloat16(W3[k * PROJ_ + c]);
    }
}

// ---------------------------------------------------------------------------
// Fused MLP, 64 pixels/block, 4 waves (unchanged).
// ---------------------------------------------------------------------------
__global__ __launch_bounds__(256) void mlp_mfma_kernel(
    const float* __restrict__ x,
    const float* __restrict__ W1, const float* __restrict__ b1,
    const short8* __restrict__ W2B, const float* __restrict__ b2,
    const short8* __restrict__ W3B, const float* __restrict__ b3,
    __hip_bfloat16* __restrict__ U)
{
    __shared__ short smem[33792];
    short* h1A = smem;
    float (*xin)[8] = (float(*)[8])(smem + 32768);

    const int t = threadIdx.x;
    const int pix0 = blockIdx.x * 64;
    const int l = t & 63, wv = t >> 6;

    {
        int idx = t;
        #pragma unroll
        for (int rep = 0; rep < 2; ++rep, idx += 256) {
            int p = idx >> 3, c = idx & 7;
            xin[p][c] = x[(pix0 + p) * DIN_ + c];
        }
    }

    {
        const int k0 = 2 * t;
        float w0[8], w1[8];
        #pragma unroll
        for (int c = 0; c < 8; ++c) {
            w0[c] = W1[c * PROJ_ + k0];
            w1[c] = W1[c * PROJ_ + k0 + 1];
        }
        const float bb0 = b1[k0], bb1 = b1[k0 + 1];
        const int kt = k0 >> 5, hi = (k0 >> 3) & 3, j = k0 & 7;
        const int base_k = (kt * 64 + hi * 16) * 8 + j;
        unsigned int* h1w = (unsigned int*)h1A;
        __syncthreads();
        for (int p = 0; p < 64; ++p) {
            float4 xa = *(const float4*)&xin[p][0];
            float4 xb = *(const float4*)&xin[p][4];
            float a0 = bb0 + xa.x*w0[0] + xa.y*w0[1] + xa.z*w0[2] + xa.w*w0[3]
                           + xb.x*w0[4] + xb.y*w0[5] + xb.z*w0[6] + xb.w*w0[7];
            float a1 = bb1 + xa.x*w1[0] + xa.y*w1[1] + xa.z*w1[2] + xa.w*w1[3]
                           + xb.x*w1[4] + xb.y*w1[5] + xb.z*w1[6] + xb.w*w1[7];
            a0 = fmaxf(a0, 0.f); a1 = fmaxf(a1, 0.f);
            unsigned int packed = (unsigned int)bfbits(a0)
                                | ((unsigned int)bfbits(a1) << 16);
            int flat = (p >> 4) * 8192 + base_k + (p & 15) * 8;
            h1w[flat >> 1] = packed;
        }
    }
    __syncthreads();

    f32x4 acc2[8];
    {
        const short8* h1f = (const short8*)h1A;
        #pragma unroll
        for (int nt = 0; nt < 8; ++nt) acc2[nt] = (f32x4){0.f, 0.f, 0.f, 0.f};
        for (int ktk = 0; ktk < 16; ++ktk) {
            short8 a = h1f[(wv * 16 + ktk) * 64 + l];
            #pragma unroll
            for (int nt = 0; nt < 8; ++nt) {
                short8 b = W2B[(nt * 16 + ktk) * 64 + l];
                acc2[nt] = __builtin_amdgcn_mfma_f32_16x16x32_bf16(a, b, acc2[nt], 0, 0, 0);
            }
        }
    }
    __syncthreads();
    short* h2A = smem;
    {
        const int r0 = (l >> 4) * 4;
        #pragma unroll
        for (int nt = 0; nt < 8; ++nt) {
            int c = nt * 16 + (l & 15);
            float bb = b2[c];
            int kt3 = c >> 5;
            int lane3base = ((c >> 3) & 3) * 16;
            #pragma unroll
            for (int q = 0; q < 4; ++q) {
                float v = fmaxf(acc2[nt][q] + bb, 0.f);
                int flat = ((wv * 4 + kt3) * 64 + lane3base + r0 + q) * 8 + (c & 7);
                h2A[flat] = (short)bfbits(v);
            }
        }
    }
    __syncthreads();

    {
        const short8* h2f = (const short8*)h2A;
        short8 a[4];
        #pragma unroll
        for (int ktk = 0; ktk < 4; ++ktk) a[ktk] = h2f[(wv * 4 + ktk) * 64 + l];
        const int r0 = (l >> 4) * 4;
        for (int pass = 0; pass < 4; ++pass) {
            f32x4 acc[8];
            #pragma unroll
            for (int nt2 = 0; nt2 < 8; ++nt2) acc[nt2] = (f32x4){0.f, 0.f, 0.f, 0.f};
            #pragma unroll
            for (int nt2 = 0; nt2 < 8; ++nt2) {
                int nt = pass * 8 + nt2;
                #pragma unroll
                for (int ktk = 0; ktk < 4; ++ktk) {
                    short8 b = W3B[(nt * 4 + ktk) * 64 + l];
                    acc[nt2] = __builtin_amdgcn_mfma_f32_16x16x32_bf16(a[ktk], b, acc[nt2], 0, 0, 0);
                }
            }
            #pragma unroll
            for (int nt2 = 0; nt2 < 8; ++nt2) {
                int c = (pass * 8 + nt2) * 16 + (l & 15);
                float bb = b3[c];
                #pragma unroll
                for (int q = 0; q < 4; ++q) {
                    U[(size_t)(pix0 + wv * 16 + r0 + q) * PROJ_ + c] =
                        __float2bfloat16(acc[nt2][q] + bb);
                }
            }
        }
    }
}

// ---------------------------------------------------------------------------
// SumN: SumN[b,y,x,ch] = sum_n U[b,n,y,x,ch]  (bf16 out).  One pass over U.
// ---------------------------------------------------------------------------
__global__ __launch_bounds__(256) void sumn_kernel(
    const unsigned int* __restrict__ U32, unsigned int* __restrict__ SumNb)
{
    const int byx = blockIdx.x;            // b*196 + yx
    const int b = byx / 196, yx = byx % 196;
    const int t = threadIdx.x;
    const unsigned int* p = U32 + ((size_t)(b * NIN_) * 196 + yx) * 256 + t;
    float a0 = 0.f, a1 = 0.f;
    #pragma unroll 8
    for (int n = 0; n < NIN_; ++n) {
        unsigned int u = p[(size_t)n * 196 * 256];
        a0 += bflo(u); a1 += bfhi(u);
    }
    SumNb[(size_t)byx * 256 + t] =
        (unsigned int)bfbits(a0) | ((unsigned int)bfbits(a1) << 16);
}

// ---------------------------------------------------------------------------
// Routing, 2-sweep form (b-linearity; v0 from SumN box-sum; no max-subtract;
// entropy in-butterfly).  1024 threads = 16 waves x 18 m-rows, 2-row ILP.
// NOTE: plain __launch_bounds__(1024) — NO min-waves arg.  Round 4's (1024,8)
// capped VGPRs at 64 and spilled to scratch (WRITE_SIZE 309 MB); (1024) alone
// caps at 128 VGPR which this kernel fits without spilling.
// ---------------------------------------------------------------------------
__global__ __launch_bounds__(1024) void route_kernel(
    const __hip_bfloat16* __restrict__ Ub,
    const unsigned short* __restrict__ SumNb,
    float* __restrict__ out_v,    // (B, NOUT, OH, OW, DOUT)
    float* __restrict__ out_ent)  // (B, M, 1, OH, OW)
{
    const uint4* __restrict__ U4 = (const uint4*)Ub;

    __shared__ int   pixoff[M_];
    __shared__ float sred[16][512];  // 32 KB
    __shared__ float sbuf[512];
    __shared__ float scl[NOUT_];
    __shared__ float vv[512];

    const int bid = blockIdx.x;
    const int xcd = bid & 7, sub = bid >> 3;   // XCD-clustered: 2 XCDs per b
    const int b  = xcd >> 1;
    const int ij = (xcd & 1) * 72 + sub;
    const int i  = ij / OW_, j = ij % OW_;
    const int t  = threadIdx.x;
    const int l  = t & 63, wv = t >> 6;        // wv 0..15
    const int no = l & 31, dh = l >> 5;
    const int ch = no * 16 + dh * 8;           // this lane's first channel

    if (t < M_) {
        int n = t / 9, r = t % 9, ki = r / 3, kj = r % 3;
        pixoff[t] = ((b * NIN_ + n) * H_ + (i + ki)) * W_ + (j + kj);
    }
    // s0 = (1/32) * 3x3 box-sum of SumN
    if (t < 512) {
        float s = 0.f;
        const int base = b * 196;
        #pragma unroll
        for (int ki = 0; ki < 3; ++ki)
            #pragma unroll
            for (int kj = 0; kj < 3; ++kj)
                s += bf2f(SumNb[(size_t)(base + (i + ki) * 14 + (j + kj)) * 512 + t]);
        sbuf[t] = s * (1.f / 32.f);
    }
    __syncthreads();
    if (t < NOUT_) {
        float ns = 0.f;
        #pragma unroll
        for (int d = 0; d < DOUT_; ++d) { float s = sbuf[t * 16 + d]; ns += s * s; }
        scl[t] = ns / (1.f + ns) * rsqrtf(ns + 1e-16f);
    }
    __syncthreads();
    if (t < 512) vv[t] = sbuf[t] * scl[t >> 4];
    __syncthreads();

    float vr[8];
    #pragma unroll
    for (int k = 0; k < 8; ++k) vr[k] = vv[ch + k];   // v0

    const int m0 = wv * 18;

    for (int pass = 1; pass <= 2; ++pass) {
        float s_acc[8] = {0,0,0,0,0,0,0,0};

        uint4 u0 = U4[(size_t)pixoff[m0] * 64 + no * 2 + dh];
        uint4 u1 = U4[(size_t)pixoff[m0 + 1] * 64 + no * 2 + dh];
        for (int r = 0; r < 18; r += 2) {
            uint4 n0 = u0, n1 = u1;
            if (r + 2 < 18) {
                n0 = U4[(size_t)pixoff[m0 + r + 2] * 64 + no * 2 + dh];
                n1 = U4[(size_t)pixoff[m0 + r + 3] * 64 + no * 2 + dh];
            }
            float dpa, dpb;
            {
                float da = bflo(u0.x)*vr[0] + bfhi(u0.x)*vr[1]
                         + bflo(u0.y)*vr[2] + bfhi(u0.y)*vr[3]
                         + bflo(u0.z)*vr[4] + bfhi(u0.z)*vr[5]
                         + bflo(u0.w)*vr[6] + bfhi(u0.w)*vr[7];
                float db = bflo(u1.x)*vr[0] + bfhi(u1.x)*vr[1]
                         + bflo(u1.y)*vr[2] + bfhi(u1.y)*vr[3]
                         + bflo(u1.z)*vr[4] + bfhi(u1.z)*vr[5]
                         + bflo(u1.w)*vr[6] + bfhi(u1.w)*vr[7];
                dpa = da + __shfl_xor(da, 32);
                dpb = db + __shfl_xor(db, 32);
            }
            float ea = __expf(dpa), eb = __expf(dpb);
            float Sa = ea, Sb = eb;
            float Ea = ea * dpa, Eb = eb * dpb;     // for entropy (pass 2)
            if (pass == 2) {
                #pragma unroll
                for (int msk = 16; msk >= 1; msk >>= 1) {
                    Sa += __shfl_xor(Sa, msk); Sb += __shfl_xor(Sb, msk);
                    Ea += __shfl_xor(Ea, msk); Eb += __shfl_xor(Eb, msk);
                }
            } else {
                #pragma unroll
                for (int msk = 16; msk >= 1; msk >>= 1) {
                    Sa += __shfl_xor(Sa, msk); Sb += __shfl_xor(Sb, msk);
                }
            }
            float ca = ea * __frcp_rn(Sa);
            float cb = eb * __frcp_rn(Sb);
            s_acc[0] += ca * bflo(u0.x) + cb * bflo(u1.x);
            s_acc[1] += ca * bfhi(u0.x) + cb * bfhi(u1.x);
            s_acc[2] += ca * bflo(u0.y) + cb * bflo(u1.y);
            s_acc[3] += ca * bfhi(u0.y) + cb * bfhi(u1.y);
            s_acc[4] += ca * bflo(u0.z) + cb * bflo(u1.z);
            s_acc[5] += ca * bfhi(u0.z) + cb * bfhi(u1.z);
            s_acc[6] += ca * bflo(u0.w) + cb * bflo(u1.w);
            s_acc[7] += ca * bfhi(u0.w) + cb * bfhi(u1.w);
            if (pass == 2 && l == 0) {
                out_ent[(b * M_ + (m0 + r)) * (OH_ * OW_) + ij] =
                    (__logf(Sa) - Ea / Sa) * 0.28853900817779268f;
                out_ent[(b * M_ + (m0 + r + 1)) * (OH_ * OW_) + ij] =
                    (__logf(Sb) - Eb / Sb) * 0.28853900817779268f;
            }
            u0 = n0; u1 = n1;
        }

        #pragma unroll
        for (int k = 0; k < 8; ++k) sred[wv][ch + k] = s_acc[k];
        __syncthreads();
        if (t < 512) {
            float ssm = 0.f;
            #pragma unroll
            for (int w2 = 0; w2 < 16; ++w2) ssm += sred[w2][t];
            sbuf[t] = ssm;
        }
        __syncthreads();
        if (t < NOUT_) {
            float ns = 0.f;
            #pragma unroll
            for (int d = 0; d < DOUT_; ++d) { float s = sbuf[t * 16 + d]; ns += s * s; }
            scl[t] = ns / (1.f + ns) * rsqrtf(ns + 1e-16f);
        }
        __syncthreads();
        if (t < 512) vv[t] = sbuf[t] * scl[t >> 4];
        __syncthreads();

        if (pass == 1) {
            #pragma unroll
            for (int k = 0; k < 8; ++k) vr[k] += vv[ch + k];   // v0 + v1
        }
    }

    if (t < 512) {
        int no2 = t >> 4, d = t & 15;
        out_v[(((b * NOUT_ + no2) * OH_ + i) * OW_ + j) * DOUT_ + d] = vv[t];
    }
}

extern "C" void kernel_launch(void* const* d_in, const int* in_sizes, int n_in,
                              void* d_out, int out_size, void* d_ws, size_t ws_size,
                              hipStream_t stream) {
    const float* x  = (const float*)d_in[0];
    const float* W1 = (const float*)d_in[1];
    const float* b1 = (const float*)d_in[2];
    const float* W2 = (const float*)d_in[3];
    const float* b2 = (const float*)d_in[4];
    const float* W3 = (const float*)d_in[5];
    const float* b3 = (const float*)d_in[6];

    // ws: U (25,690,112 B) | W2B (131,072) | W3B (131,072) | SumN bf16 (802,816)
    char* ws = (char*)d_ws;
    __hip_bfloat16* U   = (__hip_bfloat16*)ws;
    __hip_bfloat16* W2B = (__hip_bfloat16*)(ws + (size_t)NPIX_ * PROJ_ * 2);
    __hip_bfloat16* W3B = W2B + (size_t)PROJ_ * HID_;
    unsigned int*   SumNb = (unsigned int*)(W3B + (size_t)PROJ_ * HID_);

    float* out_v   = (float*)d_out;
    float* out_ent = out_v + (size_t)B_ * NOUT_ * OH_ * OW_ * DOUT_;

    hipLaunchKernelGGL(prep_kernel, dim3(256), dim3(256), 0, stream,
                       W2, W3, W2B, W3B);
    hipLaunchKernelGGL(mlp_mfma_kernel, dim3(NPIX_ / 64), dim3(256), 0, stream,
                       x, W1, b1, (const short8*)W2B, b2, (const short8*)W3B, b3, U);
    hipLaunchKernelGGL(sumn_kernel, dim3(B_ * H_ * W_), dim3(256), 0, stream,
                       (const unsigned int*)U, SumNb);
    hipLaunchKernelGGL(route_kernel, dim3(B_ * OH_ * OW_), dim3(1024), 0, stream,
                       U, (const unsigned short*)SumNb, out_v, out_ent);
}

// Round 7
// 103.283 us; speedup vs baseline: 1.2669x; 1.2669x over previous
//
#include <hip/hip_runtime.h>
#include <hip/hip_bf16.h>

#define B_ 4
#define NIN_ 32
#define H_ 14
#define W_ 14
#define DIN_ 8
#define NOUT_ 32
#define DOUT_ 16
#define K_ 3
#define OH_ 12
#define OW_ 12
#define PROJ_ 512
#define HID_ 128
#define M_ 288                  // NIN*K*K
#define NPIX_ (B_*NIN_*H_*W_)   // 25088

typedef __attribute__((ext_vector_type(8))) short short8;
typedef __attribute__((ext_vector_type(4))) float f32x4;

__device__ __forceinline__ float bflo(unsigned int u) { return __uint_as_float(u << 16); }
__device__ __forceinline__ float bfhi(unsigned int u) { return __uint_as_float(u & 0xffff0000u); }
__device__ __forceinline__ float bf2f(unsigned short u) { return __uint_as_float(((unsigned int)u) << 16); }
__device__ __forceinline__ unsigned short bfbits(float f) {
    __hip_bfloat16 h = __float2bfloat16(f);
    return *(unsigned short*)&h;
}

// ---------------------------------------------------------------------------
// Prep: W2 (512x128) and W3 (128x512) f32 -> bf16 in MFMA B-fragment order.
// ---------------------------------------------------------------------------
__global__ __launch_bounds__(256) void prep_kernel(
    const float* __restrict__ W2, const float* __restrict__ W3,
    __hip_bfloat16* __restrict__ W2B, __hip_bfloat16* __restrict__ W3B)
{
    int idx = blockIdx.x * 256 + threadIdx.x;  // [0, 65536)
    {
        int j = idx & 7, lane = (idx >> 3) & 63, kt = (idx >> 9) & 15, nt = idx >> 13;
        int k = kt * 32 + (lane >> 4) * 8 + j;
        int c = nt * 16 + (lane & 15);
        W2B[idx] = __float2bfloat16(W2[k * HID_ + c]);
    }
    {
        int j = idx & 7, lane = (idx >> 3) & 63, kt = (idx >> 9) & 3, nt = idx >> 11;
        int k = kt * 32 + (lane >> 4) * 8 + j;
        int c = nt * 16 + (lane & 15);
        W3B[idx] = __float2bfloat16(W3[k * PROJ_ + c]);
    }
}

// ---------------------------------------------------------------------------
// Fused MLP, 64 pixels/block, 4 waves (unchanged).
// ---------------------------------------------------------------------------
__global__ __launch_bounds__(256) void mlp_mfma_kernel(
    const float* __restrict__ x,
    const float* __restrict__ W1, const float* __restrict__ b1,
    const short8* __restrict__ W2B, const float* __restrict__ b2,
    const short8* __restrict__ W3B, const float* __restrict__ b3,
    __hip_bfloat16* __restrict__ U)
{
    __shared__ short smem[33792];
    short* h1A = smem;
    float (*xin)[8] = (float(*)[8])(smem + 32768);

    const int t = threadIdx.x;
    const int pix0 = blockIdx.x * 64;
    const int l = t & 63, wv = t >> 6;

    {
        int idx = t;
        #pragma unroll
        for (int rep = 0; rep < 2; ++rep, idx += 256) {
            int p = idx >> 3, c = idx & 7;
            xin[p][c] = x[(pix0 + p) * DIN_ + c];
        }
    }

    {
        const int k0 = 2 * t;
        float w0[8], w1[8];
        #pragma unroll
        for (int c = 0; c < 8; ++c) {
            w0[c] = W1[c * PROJ_ + k0];
            w1[c] = W1[c * PROJ_ + k0 + 1];
        }
        const float bb0 = b1[k0], bb1 = b1[k0 + 1];
        const int kt = k0 >> 5, hi = (k0 >> 3) & 3, j = k0 & 7;
        const int base_k = (kt * 64 + hi * 16) * 8 + j;
        unsigned int* h1w = (unsigned int*)h1A;
        __syncthreads();
        for (int p = 0; p < 64; ++p) {
            float4 xa = *(const float4*)&xin[p][0];
            float4 xb = *(const float4*)&xin[p][4];
            float a0 = bb0 + xa.x*w0[0] + xa.y*w0[1] + xa.z*w0[2] + xa.w*w0[3]
                           + xb.x*w0[4] + xb.y*w0[5] + xb.z*w0[6] + xb.w*w0[7];
            float a1 = bb1 + xa.x*w1[0] + xa.y*w1[1] + xa.z*w1[2] + xa.w*w1[3]
                           + xb.x*w1[4] + xb.y*w1[5] + xb.z*w1[6] + xb.w*w1[7];
            a0 = fmaxf(a0, 0.f); a1 = fmaxf(a1, 0.f);
            unsigned int packed = (unsigned int)bfbits(a0)
                                | ((unsigned int)bfbits(a1) << 16);
            int flat = (p >> 4) * 8192 + base_k + (p & 15) * 8;
            h1w[flat >> 1] = packed;
        }
    }
    __syncthreads();

    f32x4 acc2[8];
    {
        const short8* h1f = (const short8*)h1A;
        #pragma unroll
        for (int nt = 0; nt < 8; ++nt) acc2[nt] = (f32x4){0.f, 0.f, 0.f, 0.f};
        for (int ktk = 0; ktk < 16; ++ktk) {
            short8 a = h1f[(wv * 16 + ktk) * 64 + l];
            #pragma unroll
            for (int nt = 0; nt < 8; ++nt) {
                short8 b = W2B[(nt * 16 + ktk) * 64 + l];
                acc2[nt] = __builtin_amdgcn_mfma_f32_16x16x32_bf16(a, b, acc2[nt], 0, 0, 0);
            }
        }
    }
    __syncthreads();
    short* h2A = smem;
    {
        const int r0 = (l >> 4) * 4;
        #pragma unroll
        for (int nt = 0; nt < 8; ++nt) {
            int c = nt * 16 + (l & 15);
            float bb = b2[c];
            int kt3 = c >> 5;
            int lane3base = ((c >> 3) & 3) * 16;
            #pragma unroll
            for (int q = 0; q < 4; ++q) {
                float v = fmaxf(acc2[nt][q] + bb, 0.f);
                int flat = ((wv * 4 + kt3) * 64 + lane3base + r0 + q) * 8 + (c & 7);
                h2A[flat] = (short)bfbits(v);
            }
        }
    }
    __syncthreads();

    {
        const short8* h2f = (const short8*)h2A;
        short8 a[4];
        #pragma unroll
        for (int ktk = 0; ktk < 4; ++ktk) a[ktk] = h2f[(wv * 4 + ktk) * 64 + l];
        const int r0 = (l >> 4) * 4;
        for (int pass = 0; pass < 4; ++pass) {
            f32x4 acc[8];
            #pragma unroll
            for (int nt2 = 0; nt2 < 8; ++nt2) acc[nt2] = (f32x4){0.f, 0.f, 0.f, 0.f};
            #pragma unroll
            for (int nt2 = 0; nt2 < 8; ++nt2) {
                int nt = pass * 8 + nt2;
                #pragma unroll
                for (int ktk = 0; ktk < 4; ++ktk) {
                    short8 b = W3B[(nt * 4 + ktk) * 64 + l];
                    acc[nt2] = __builtin_amdgcn_mfma_f32_16x16x32_bf16(a[ktk], b, acc[nt2], 0, 0, 0);
                }
            }
            #pragma unroll
            for (int nt2 = 0; nt2 < 8; ++nt2) {
                int c = (pass * 8 + nt2) * 16 + (l & 15);
                float bb = b3[c];
                #pragma unroll
                for (int q = 0; q < 4; ++q) {
                    U[(size_t)(pix0 + wv * 16 + r0 + q) * PROJ_ + c] =
                        __float2bfloat16(acc[nt2][q] + bb);
                }
            }
        }
    }
}

// ---------------------------------------------------------------------------
// SumN: SumN[b,y,x,ch] = sum_n U[b,n,y,x,ch]  (bf16 out).  One pass over U.
// ---------------------------------------------------------------------------
__global__ __launch_bounds__(256) void sumn_kernel(
    const unsigned int* __restrict__ U32, unsigned int* __restrict__ SumNb)
{
    const int byx = blockIdx.x;            // b*196 + yx
    const int b = byx / 196, yx = byx % 196;
    const int t = threadIdx.x;
    const unsigned int* p = U32 + ((size_t)(b * NIN_) * 196 + yx) * 256 + t;
    float a0 = 0.f, a1 = 0.f;
    #pragma unroll 8
    for (int n = 0; n < NIN_; ++n) {
        unsigned int u = p[(size_t)n * 196 * 256];
        a0 += bflo(u); a1 += bfhi(u);
    }
    SumNb[(size_t)byx * 256 + t] =
        (unsigned int)bfbits(a0) | ((unsigned int)bfbits(a1) << 16);
}

// ---------------------------------------------------------------------------
// Routing, 2-sweep form, row-per-half-wave mapping.
// lane = (no, row-parity): lanes 0-31 own row 2c (one no each, all 16 d in
// regs), lanes 32-63 own row 2c+1.  Dot needs NO cross-lane op; softmax is a
// single 5-stage butterfly within the 32-lane group; exp/rcp once per lane.
// All LDS staging transposed [d][no] (pad 33) -> conflict-free.
// 512 threads = 8 waves x 36 rows.  Plain __launch_bounds__(512) (no
// min-waves: round 4's (1024,8) spilled — WRITE_SIZE 309 MB).
// ---------------------------------------------------------------------------
__global__ __launch_bounds__(512) void route_kernel(
    const __hip_bfloat16* __restrict__ Ub,
    const unsigned short* __restrict__ SumNb,
    float* __restrict__ out_v,    // (B, NOUT, OH, OW, DOUT)
    float* __restrict__ out_ent)  // (B, M, 1, OH, OW)
{
    const uint4* __restrict__ U4 = (const uint4*)Ub;

    __shared__ int   pixoff[M_];
    __shared__ float sredT[16][16][33];  // [halfwave][d][no]  33.8 KB
    __shared__ float sbufT[16][33];      // [d][no]
    __shared__ float vvT[16][33];        // [d][no]
    __shared__ float scl[NOUT_];

    const int bid = blockIdx.x;
    const int xcd = bid & 7, sub = bid >> 3;   // XCD-clustered: 2 XCDs per b
    const int b  = xcd >> 1;
    const int ij = (xcd & 1) * 72 + sub;
    const int i  = ij / OW_, j = ij % OW_;
    const int t  = threadIdx.x;
    const int l  = t & 63, wv = t >> 6;        // wv 0..7
    const int no = l & 31, half = l >> 5;
    const int hw = wv * 2 + half;              // halfwave 0..15

    if (t < M_) {
        int n = t / 9, r = t % 9, ki = r / 3, kj = r % 3;
        pixoff[t] = ((b * NIN_ + n) * H_ + (i + ki)) * W_ + (j + kj);
    }
    // s0 = (1/32) * 3x3 box-sum of SumN   (t = ch = no_c*16 + d_c, coalesced)
    {
        float s = 0.f;
        const int base = b * 196;
        #pragma unroll
        for (int ki = 0; ki < 3; ++ki)
            #pragma unroll
            for (int kj = 0; kj < 3; ++kj)
                s += bf2f(SumNb[(size_t)(base + (i + ki) * 14 + (j + kj)) * 512 + t]);
        sbufT[t & 15][t >> 4] = s * (1.f / 32.f);
    }
    __syncthreads();
    if (t < NOUT_) {
        float ns = 0.f;
        #pragma unroll
        for (int d = 0; d < DOUT_; ++d) { float s = sbufT[d][t]; ns += s * s; }
        scl[t] = ns / (1.f + ns) * rsqrtf(ns + 1e-16f);
    }
    __syncthreads();
    vvT[t >> 5][t & 31] = sbufT[t >> 5][t & 31] * scl[t & 31];
    __syncthreads();

    float vr[16];
    #pragma unroll
    for (int k = 0; k < 16; ++k) vr[k] = vvT[k][no];   // v0

    const int mbase = wv * 36;

    for (int pass = 1; pass <= 2; ++pass) {
        float s_acc[16];
        #pragma unroll
        for (int k = 0; k < 16; ++k) s_acc[k] = 0.f;

        // prefetch row 0/1
        uint4 p0, p1;
        {
            size_t base = (size_t)pixoff[mbase + half] * 64 + no * 2;
            p0 = U4[base]; p1 = U4[base + 1];
        }
        for (int c = 0; c < 18; ++c) {
            uint4 q0 = p0, q1 = p1;
            if (c + 1 < 18) {
                size_t base = (size_t)pixoff[mbase + 2 * (c + 1) + half] * 64 + no * 2;
                p0 = U4[base]; p1 = U4[base + 1];
            }
            float pv[16];
            pv[0]=bflo(q0.x);  pv[1]=bfhi(q0.x);  pv[2]=bflo(q0.y);  pv[3]=bfhi(q0.y);
            pv[4]=bflo(q0.z);  pv[5]=bfhi(q0.z);  pv[6]=bflo(q0.w);  pv[7]=bfhi(q0.w);
            pv[8]=bflo(q1.x);  pv[9]=bfhi(q1.x);  pv[10]=bflo(q1.y); pv[11]=bfhi(q1.y);
            pv[12]=bflo(q1.z); pv[13]=bfhi(q1.z); pv[14]=bflo(q1.w); pv[15]=bfhi(q1.w);

            // dot (4 parallel partials -> tree)
            float d0 = pv[0]*vr[0] + pv[4]*vr[4] + pv[8]*vr[8]  + pv[12]*vr[12];
            float d1 = pv[1]*vr[1] + pv[5]*vr[5] + pv[9]*vr[9]  + pv[13]*vr[13];
            float d2 = pv[2]*vr[2] + pv[6]*vr[6] + pv[10]*vr[10]+ pv[14]*vr[14];
            float d3 = pv[3]*vr[3] + pv[7]*vr[7] + pv[11]*vr[11]+ pv[15]*vr[15];
            float dp = (d0 + d1) + (d2 + d3);

            float e = __expf(dp);
            float S = e;
            if (pass == 2) {
                float E = e * dp;
                #pragma unroll
                for (int msk = 16; msk >= 1; msk >>= 1) {
                    S += __shfl_xor(S, msk);
                    E += __shfl_xor(E, msk);
                }
                if (no == 0)
                    out_ent[(b * M_ + (mbase + 2 * c + half)) * (OH_ * OW_) + ij] =
                        (__logf(S) - E / S) * 0.28853900817779268f;  // 1/log 32
                float cc = e * __frcp_rn(S);
                #pragma unroll
                for (int k = 0; k < 16; ++k) s_acc[k] += cc * pv[k];
            } else {
                #pragma unroll
                for (int msk = 16; msk >= 1; msk >>= 1)
                    S += __shfl_xor(S, msk);
                float cc = e * __frcp_rn(S);
                #pragma unroll
                for (int k = 0; k < 16; ++k) s_acc[k] += cc * pv[k];
            }
        }

        // cross-(half)wave s reduction, transposed conflict-free
        #pragma unroll
        for (int k = 0; k < 16; ++k) sredT[hw][k][no] = s_acc[k];
        __syncthreads();
        {
            int d = t >> 5, n2 = t & 31;
            float ssm = 0.f;
            #pragma unroll
            for (int h2 = 0; h2 < 16; ++h2) ssm += sredT[h2][d][n2];
            sbufT[d][n2] = ssm;
        }
        __syncthreads();
        if (t < NOUT_) {
            float ns = 0.f;
            #pragma unroll
            for (int d = 0; d < DOUT_; ++d) { float s = sbufT[d][t]; ns += s * s; }
            scl[t] = ns / (1.f + ns) * rsqrtf(ns + 1e-16f);
        }
        __syncthreads();
        vvT[t >> 5][t & 31] = sbufT[t >> 5][t & 31] * scl[t & 31];
        __syncthreads();

        if (pass == 1) {
            #pragma unroll
            for (int k = 0; k < 16; ++k) vr[k] += vvT[k][no];   // v0 + v1
        }
    }

    {   // final v output (vvT holds v2)
        int no2 = t >> 4, d = t & 15;
        out_v[(((b * NOUT_ + no2) * OH_ + i) * OW_ + j) * DOUT_ + d] = vvT[d][no2];
    }
}

extern "C" void kernel_launch(void* const* d_in, const int* in_sizes, int n_in,
                              void* d_out, int out_size, void* d_ws, size_t ws_size,
                              hipStream_t stream) {
    const float* x  = (const float*)d_in[0];
    const float* W1 = (const float*)d_in[1];
    const float* b1 = (const float*)d_in[2];
    const float* W2 = (const float*)d_in[3];
    const float* b2 = (const float*)d_in[4];
    const float* W3 = (const float*)d_in[5];
    const float* b3 = (const float*)d_in[6];

    // ws: U (25,690,112 B) | W2B (131,072) | W3B (131,072) | SumN bf16 (802,816)
    char* ws = (char*)d_ws;
    __hip_bfloat16* U   = (__hip_bfloat16*)ws;
    __hip_bfloat16* W2B = (__hip_bfloat16*)(ws + (size_t)NPIX_ * PROJ_ * 2);
    __hip_bfloat16* W3B = W2B + (size_t)PROJ_ * HID_;
    unsigned int*   SumNb = (unsigned int*)(W3B + (size_t)PROJ_ * HID_);

    float* out_v   = (float*)d_out;
    float* out_ent = out_v + (size_t)B_ * NOUT_ * OH_ * OW_ * DOUT_;

    hipLaunchKernelGGL(prep_kernel, dim3(256), dim3(256), 0, stream,
                       W2, W3, W2B, W3B);
    hipLaunchKernelGGL(mlp_mfma_kernel, dim3(NPIX_ / 64), dim3(256), 0, stream,
                       x, W1, b1, (const short8*)W2B, b2, (const short8*)W3B, b3, U);
    hipLaunchKernelGGL(sumn_kernel, dim3(B_ * H_ * W_), dim3(256), 0, stream,
                       (const unsigned int*)U, SumNb);
    hipLaunchKernelGGL(route_kernel, dim3(B_ * OH_ * OW_), dim3(512), 0, stream,
                       U, (const unsigned short*)SumNb, out_v, out_ent);
}